// Round 11
// baseline (433.126 us; speedup 1.0000x reference)
//
#include <hip/hip_runtime.h>
#include <math.h>

#define DD 128
#define HH 32
#define MH 64
#define TT 256
#define ETA_C 1e-3f
#define BOUND_C 1.4907119849998598f   // sqrt(2/0.9)

// ws float layout:
//   F[32][128] @ 0     fn2[32] @ 8192   s4[32] @ 8224   m0n2[32] @ 8256
//   P[32][128] @ 4096
//   X store @ 8320 (257*128)   U store @ 41216 (256*128)
#define WSX 8320
#define WSU 41216

typedef float v2f __attribute__((ext_vector_type(2)));

#define KEEPV(v) asm volatile("" : "+v"(v))

template <int CTRL>
__device__ __forceinline__ float dpp_add(float x) {
    int y = __builtin_amdgcn_update_dpp(0, __float_as_int(x), CTRL, 0xF, 0xF, true);
    return x + __int_as_float(y);
}
// 0xB1 quad xor1, 0x4E quad xor2, 0x104 row_shl:4 (lane i <- lane i+4),
// 0x124 row_ror:4, 0x128 row_ror:8

__global__ void k_precompF(const float* __restrict__ W, const float* __restrict__ phi,
                           const float* __restrict__ sigma, float* __restrict__ ws) {
    int i = blockIdx.x, d = threadIdx.x;
    float acc = 0.f;
#pragma unroll
    for (int m = 0; m < MH; ++m) acc += W[d * MH + m] * phi[m * HH + i];
    ws[i * DD + d] = acc;
    __shared__ float red[DD];
    red[d] = acc * acc;
    __syncthreads();
    for (int o = 64; o > 0; o >>= 1) {
        if (d < o) red[d] += red[d + o];
        __syncthreads();
    }
    if (d == 0) {
        ws[8192 + i] = red[0];
        ws[8224 + i] = sqrtf(sqrtf(sigma[i]));
    }
}

__global__ void k_precompP(const float* __restrict__ M0, float* __restrict__ ws) {
    int i = blockIdx.x, n = threadIdx.x;
    const float* f  = ws + i * DD;
    const float* m0 = M0 + i * DD * DD + n * DD;
    float p = 0.f, sq = 0.f;
#pragma unroll 4
    for (int d = 0; d < DD; ++d) {
        float v = m0[d];
        p  += v * f[d];
        sq += v * v;
    }
    ws[4096 + i * DD + n] = p;
    __shared__ float red[DD];
    red[n] = sq;
    __syncthreads();
    for (int o = 64; o > 0; o >>= 1) {
        if (n < o) red[n] += red[n + o];
        __syncthreads();
    }
    if (n == 0) ws[8256 + i] = red[0];
}

__launch_bounds__(1024)
__global__ void k_scan(const float* __restrict__ Am, const float* __restrict__ Bm,
                       const float* __restrict__ Rm, const float* __restrict__ Km,
                       const float* __restrict__ x0, const float* __restrict__ wseq,
                       float* __restrict__ ws) {
    const int tid = threadIdx.x;
    const int r = tid >> 3, s = tid & 7;

    // Occupancy pin: make static LDS > 80 KB so the compiler KNOWS only one
    // 1024-thread workgroup fits per CU -> VGPR budget 128 (not 64) -> the
    // 64 matrix floats below can stay register-resident. The asm escape
    // prevents elimination of the (otherwise unused) pad array.
    __shared__ float occupancy_pad[16000];
    asm volatile("" :: "s"(occupancy_pad) : "memory");

    // Thread owns row r, cols {4s+32q+0..3}, q=0..3. 64 matrix VGPRs/thread.
    v2f mK[8], mA[8], mB[8], mR[8];
#pragma unroll
    for (int q = 0; q < 4; ++q) {
        const int col = 4 * s + 32 * q;
        float4 v;
        v = *(const float4*)(Km + r * DD + col);
        mK[2*q] = v2f{v.x, v.y}; mK[2*q+1] = v2f{v.z, v.w};
        v = *(const float4*)(Am + r * DD + col);
        mA[2*q] = v2f{v.x, v.y}; mA[2*q+1] = v2f{v.z, v.w};
        v = *(const float4*)(Bm + r * DD + col);
        mB[2*q] = v2f{v.x, v.y}; mB[2*q+1] = v2f{v.z, v.w};
        v = *(const float4*)(Rm + r * DD + col);
        v.x += Rm[(col + 0) * DD + r];   // Rsym = R + R^T
        v.y += Rm[(col + 1) * DD + r];
        v.z += Rm[(col + 2) * DD + r];
        v.w += Rm[(col + 3) * DD + r];
        mR[2*q] = v2f{v.x, v.y}; mR[2*q+1] = v2f{v.z, v.w};
    }
#pragma unroll
    for (int q = 0; q < 8; ++q) { KEEPV(mK[q]); KEEPV(mA[q]); KEEPV(mB[q]); KEEPV(mR[q]); }

    // Filter state (first 512 threads): filter oi = tid>>4, elems on0..on0+7.
    const int oi = tid >> 4, ol = tid & 15, on0 = ol << 3;
    float y[8], p[8];
    float oa = 1.f, ony2 = 0.f, oyp = 0.f;
    float os4 = 0.f, ofn2 = 0.f, om0 = 0.f, oe = 0.f;

    __shared__ float xs[2][DD];
    __shared__ float us[DD], gs[DD];
    __shared__ float Zl[HH * 131];   // odd stride: conflict-free z-fold reads

    if (tid < 512) {
        os4  = ws[8224 + oi];
        ofn2 = ws[8192 + oi];
        om0  = ws[8256 + oi];
        oe   = ETA_C * os4;
#pragma unroll
        for (int j = 0; j < 8; ++j) {
            y[j] = 0.f;
            p[j] = ws[4096 + oi * DD + on0 + j];
        }
#pragma unroll
        for (int j = 0; j < 8; ++j) Zl[oi * 131 + on0 + j] = os4 * p[j];
    }
    if (tid < DD) {
        float xv = x0[tid];
        xs[0][tid] = xv;
        ws[WSX + tid] = xv;
    }
    __syncthreads();

    float axr = 0.f;
#pragma unroll 1
    for (int t = 0; t < TT; ++t) {
        float* xcur = xs[t & 1];
        float* xnxt = xs[(t & 1) ^ 1];
        float wv = 0.f;
        if (s == 0) wv = wseq[t * DD + r];   // prefetch, consumed in phase B

        // ---- phase A: u[r] = noise[r] - (K x)[r]; (A x)[r] partial kept in reg
        {
            const float4* x4p = (const float4*)xcur;
            v2f aK = v2f{0.f, 0.f}, aA = v2f{0.f, 0.f};
#pragma unroll
            for (int q = 0; q < 4; ++q) {
                float4 xq = x4p[s + 8 * q];
                v2f lo = v2f{xq.x, xq.y}, hi = v2f{xq.z, xq.w};
                aK += mK[2*q] * lo; aK += mK[2*q+1] * hi;
                aA += mA[2*q] * lo; aA += mA[2*q+1] * hi;
            }
            float zp = 0.f;
#pragma unroll
            for (int j = 0; j < 4; ++j) zp += Zl[(4 * s + j) * 131 + r];
            float uval = zp - (aK.x + aK.y);
            float av = aA.x + aA.y;
            uval = dpp_add<0xB1>(uval); uval = dpp_add<0x4E>(uval); uval = dpp_add<0x104>(uval);
            av   = dpp_add<0xB1>(av);   av   = dpp_add<0x4E>(av);   av   = dpp_add<0x104>(av);
            if (s == 0) {
                us[r] = uval;
                ws[WSU + t * DD + r] = uval;   // for deferred cost kernel
            }
            axr = av;
        }
        asm volatile("s_waitcnt lgkmcnt(0)" ::: "memory");
        __builtin_amdgcn_s_barrier();

        // ---- phase B: g = Rsym u ; x_next = Ax + Bu + w
        {
            const float4* u4p = (const float4*)us;
            v2f aR = v2f{0.f, 0.f}, aB = v2f{0.f, 0.f};
#pragma unroll
            for (int q = 0; q < 4; ++q) {
                float4 uq = u4p[s + 8 * q];
                v2f lo = v2f{uq.x, uq.y}, hi = v2f{uq.z, uq.w};
                aR += mR[2*q] * lo; aR += mR[2*q+1] * hi;
                aB += mB[2*q] * lo; aB += mB[2*q+1] * hi;
            }
            float gv = aR.x + aR.y, bv = aB.x + aB.y;
            gv = dpp_add<0xB1>(gv); gv = dpp_add<0x4E>(gv); gv = dpp_add<0x104>(gv);
            bv = dpp_add<0xB1>(bv); bv = dpp_add<0x4E>(bv); bv = dpp_add<0x104>(bv);
            if (s == 0) {
                gs[r] = gv;
                float xn = axr + bv + wv;
                xnxt[r] = xn;
                ws[WSX + (t + 1) * DD + r] = xn;
            }
        }
        asm volatile("s_waitcnt lgkmcnt(0)" ::: "memory");
        __builtin_amdgcn_s_barrier();

        // ---- phase C: filter update with incremental norm tracking (tid<512)
        if (tid < 512) {
            const float4* g4 = (const float4*)(gs + on0);
            float4 ga = g4[0], gb = g4[1];
            float g8[8] = {ga.x, ga.y, ga.z, ga.w, gb.x, gb.y, gb.z, gb.w};
            float yg = 0.f, gp = 0.f, g2 = 0.f;
#pragma unroll
            for (int j = 0; j < 8; ++j) {
                yg += y[j] * g8[j];
                gp += p[j] * g8[j];
                g2 += g8[j] * g8[j];
            }
            yg = dpp_add<0xB1>(yg); yg = dpp_add<0x4E>(yg);
            yg = dpp_add<0x124>(yg); yg = dpp_add<0x128>(yg);
            gp = dpp_add<0xB1>(gp); gp = dpp_add<0x4E>(gp);
            gp = dpp_add<0x124>(gp); gp = dpp_add<0x128>(gp);
            g2 = dpp_add<0xB1>(g2); g2 = dpp_add<0x4E>(g2);
            g2 = dpp_add<0x124>(g2); g2 = dpp_add<0x128>(g2);
            float ny2 = ony2 - 2.f * oe * yg + oe * oe * g2;
            float yp  = oyp - oe * gp;
            float norm2 = oa * oa * om0 + 2.f * oa * yp + ofn2 * ny2;
            float nrm = sqrtf(fmaxf(norm2, 0.f));
            float sc = (nrm > BOUND_C) ? (BOUND_C / nrm) : 1.f;
            oa *= sc; ony2 = ny2 * sc * sc; oyp = yp * sc;
            float ca = os4 * oa, cy = os4 * ofn2;
#pragma unroll
            for (int j = 0; j < 8; ++j) {
                y[j] = sc * (y[j] - oe * g8[j]);
                Zl[oi * 131 + on0 + j] = ca * p[j] + cy * y[j];
            }
        }
        asm volatile("s_waitcnt lgkmcnt(0)" ::: "memory");
        __builtin_amdgcn_s_barrier();
    }
}

// Deferred, fully parallel cost: out[t] = x_t' Q x_t + u_t' R u_t
__launch_bounds__(128)
__global__ void k_cost(const float* __restrict__ Qm, const float* __restrict__ Rm,
                       const float* __restrict__ ws, float* __restrict__ out) {
    const int t = blockIdx.x, r = threadIdx.x;
    __shared__ float xv[DD], uv[DD];
    __shared__ float red[2];
    xv[r] = ws[WSX + t * DD + r];
    uv[r] = ws[WSU + t * DD + r];
    __syncthreads();
    const float4* q4 = (const float4*)(Qm + r * DD);
    const float4* r4 = (const float4*)(Rm + r * DD);
    const float4* x4 = (const float4*)xv;
    const float4* u4 = (const float4*)uv;
    float qa = 0.f, ra = 0.f;
#pragma unroll 8
    for (int j = 0; j < 32; ++j) {
        float4 qv = q4[j], xq = x4[j];
        qa += qv.x*xq.x + qv.y*xq.y + qv.z*xq.z + qv.w*xq.w;
        float4 rv = r4[j], uq = u4[j];
        ra += rv.x*uq.x + rv.y*uq.y + rv.z*uq.z + rv.w*uq.w;
    }
    float part = xv[r] * qa + uv[r] * ra;
    part = dpp_add<0xB1>(part); part = dpp_add<0x4E>(part);
    part = dpp_add<0x124>(part); part = dpp_add<0x128>(part);
    part += __shfl_xor(part, 16); part += __shfl_xor(part, 32);
    if ((r & 63) == 0) red[r >> 6] = part;
    __syncthreads();
    if (r == 0) out[t] = red[0] + red[1];
}

extern "C" void kernel_launch(void* const* d_in, const int* in_sizes, int n_in,
                              void* d_out, int out_size, void* d_ws, size_t ws_size,
                              hipStream_t stream) {
    const float* A     = (const float*)d_in[0];
    const float* B     = (const float*)d_in[1];
    const float* Q     = (const float*)d_in[2];
    const float* R     = (const float*)d_in[3];
    const float* K     = (const float*)d_in[4];
    const float* sigma = (const float*)d_in[5];
    const float* phi   = (const float*)d_in[6];
    const float* M0    = (const float*)d_in[7];
    const float* x0    = (const float*)d_in[8];
    const float* Whist = (const float*)d_in[9];
    const float* wseq  = (const float*)d_in[10];
    float* out = (float*)d_out;
    float* ws  = (float*)d_ws;

    hipLaunchKernelGGL(k_precompF, dim3(HH), dim3(DD), 0, stream, Whist, phi, sigma, ws);
    hipLaunchKernelGGL(k_precompP, dim3(HH), dim3(DD), 0, stream, M0, ws);
    hipLaunchKernelGGL(k_scan, dim3(1), dim3(1024), 0, stream,
                       A, B, R, K, x0, wseq, ws);
    hipLaunchKernelGGL(k_cost, dim3(TT), dim3(DD), 0, stream, Q, R, ws, out);
}

// Round 12
// 369.563 us; speedup vs baseline: 1.1720x; 1.1720x over previous
//
#include <hip/hip_runtime.h>
#include <math.h>

#define DD 128
#define HH 32
#define MH 64
#define TT 256
#define ETA_C 1e-3f
#define BOUND_C 1.4907119849998598f   // sqrt(2/0.9)

// ws float layout:
//   F[32][128] @ 0     fn2[32] @ 8192   s4[32] @ 8224   m0n2[32] @ 8256
//   P[32][128] @ 4096
//   X store @ 8320 (257*128)   U store @ 41216 (256*128)
#define WSX 8320
#define WSU 41216

typedef float v2f __attribute__((ext_vector_type(2)));

// Force value into a register and make it non-rematerializable.
#define KEEPV(v) asm volatile("" : "+v"(v))

template <int CTRL>
__device__ __forceinline__ float dpp_add(float x) {
    int y = __builtin_amdgcn_update_dpp(0, __float_as_int(x), CTRL, 0xF, 0xF, true);
    return x + __int_as_float(y);
}
// quad sum: 0xB1,0x4E.  16-lane sum: +0x124 (row_ror:4), 0x128 (row_ror:8).

__global__ void k_precompF(const float* __restrict__ W, const float* __restrict__ phi,
                           const float* __restrict__ sigma, float* __restrict__ ws) {
    int i = blockIdx.x, d = threadIdx.x;
    float acc = 0.f;
#pragma unroll
    for (int m = 0; m < MH; ++m) acc += W[d * MH + m] * phi[m * HH + i];
    ws[i * DD + d] = acc;
    __shared__ float red[DD];
    red[d] = acc * acc;
    __syncthreads();
    for (int o = 64; o > 0; o >>= 1) {
        if (d < o) red[d] += red[d + o];
        __syncthreads();
    }
    if (d == 0) {
        ws[8192 + i] = red[0];
        ws[8224 + i] = sqrtf(sqrtf(sigma[i]));
    }
}

__global__ void k_precompP(const float* __restrict__ M0, float* __restrict__ ws) {
    int i = blockIdx.x, n = threadIdx.x;
    const float* f  = ws + i * DD;
    const float* m0 = M0 + i * DD * DD + n * DD;
    float p = 0.f, sq = 0.f;
#pragma unroll 4
    for (int d = 0; d < DD; ++d) {
        float v = m0[d];
        p  += v * f[d];
        sq += v * v;
    }
    ws[4096 + i * DD + n] = p;
    __shared__ float red[DD];
    red[n] = sq;
    __syncthreads();
    for (int o = 64; o > 0; o >>= 1) {
        if (n < o) red[n] += red[n + o];
        __syncthreads();
    }
    if (n == 0) ws[8256 + i] = red[0];
}

__launch_bounds__(512)
__attribute__((amdgpu_waves_per_eu(2, 2)))
__global__ void k_scan(const float* __restrict__ Am, const float* __restrict__ Bm,
                       const float* __restrict__ Rm, const float* __restrict__ Km,
                       const float* __restrict__ x0, const float* __restrict__ wseq,
                       float* __restrict__ ws) {
    const int tid = threadIdx.x;
    const int r = tid >> 2, s = tid & 3;

    // Column-pair layout: thread (r,s) owns cols {2s+8q, 2s+8q+1}, q=0..15.
    // Per-q LDS broadcast reads hit 4 distinct bank-pairs -> conflict-free.
    v2f mK[16], mA[16], mB[16], mR[16];
#pragma unroll
    for (int q = 0; q < 16; ++q) {
        const int col = 2 * s + 8 * q;
        mK[q] = *(const v2f*)(Km + r * DD + col);
        mA[q] = *(const v2f*)(Am + r * DD + col);
        mB[q] = *(const v2f*)(Bm + r * DD + col);
        v2f rv = *(const v2f*)(Rm + r * DD + col);
        rv.x += Rm[col * DD + r];          // Rsym = R + R^T
        rv.y += Rm[(col + 1) * DD + r];
        mR[q] = rv;
    }
#pragma unroll
    for (int q = 0; q < 16; ++q) { KEEPV(mK[q]); KEEPV(mA[q]); KEEPV(mB[q]); KEEPV(mR[q]); }

    // Filter state: filter oi owned by 16 consecutive threads, 8 elems each.
    const int oi = tid >> 4, ol = tid & 15, on0 = ol << 3;
    float y[8], p[8];
    float oa = 1.f, ony2 = 0.f, oyp = 0.f;
    const float os4  = ws[8224 + oi];
    const float ofn2 = ws[8192 + oi];
    const float om0  = ws[8256 + oi];
    const float oe   = ETA_C * os4;

    __shared__ float xs[2][DD];
    __shared__ float us[DD], gs[DD];
    __shared__ float Zl[HH * 131];   // stride 131: z-sum reads conflict-free

#pragma unroll
    for (int j = 0; j < 8; ++j) {
        y[j] = 0.f;
        p[j] = ws[4096 + oi * DD + on0 + j];
    }
#pragma unroll
    for (int j = 0; j < 8; ++j) Zl[oi * 131 + on0 + j] = os4 * p[j];
    if (tid < DD) {
        float xv = x0[tid];
        xs[0][tid] = xv;
        ws[WSX + tid] = xv;
    }
    __syncthreads();

    float axr = 0.f;
#pragma unroll 1
    for (int t = 0; t < TT; ++t) {
        float* xcur = xs[t & 1];
        float* xnxt = xs[(t & 1) ^ 1];
        float wv = 0.f;
        if (s == 0) wv = wseq[t * DD + r];   // prefetch, consumed in phase B

        // ---- phase A: u[r] = noise[r] - (K x)[r]; (A x)[r] partial kept in reg
        {
            const v2f* x2 = (const v2f*)xcur;
            v2f aK = v2f{0.f, 0.f}, aA = v2f{0.f, 0.f};
#pragma unroll
            for (int q = 0; q < 16; ++q) {
                v2f xq = x2[s + 4 * q];
                aK += mK[q] * xq;
                aA += mA[q] * xq;
            }
            float zp = 0.f;
#pragma unroll
            for (int j = 0; j < 8; ++j) zp += Zl[(8 * s + j) * 131 + r];
            float uval = zp - (aK.x + aK.y);
            float av = aA.x + aA.y;
            uval = dpp_add<0xB1>(uval); uval = dpp_add<0x4E>(uval);
            av   = dpp_add<0xB1>(av);   av   = dpp_add<0x4E>(av);
            if (s == 0) {
                us[r] = uval;
                ws[WSU + t * DD + r] = uval;   // for deferred cost kernel
            }
            axr = av;
        }
        asm volatile("s_waitcnt lgkmcnt(0)" ::: "memory");
        __builtin_amdgcn_s_barrier();

        // ---- phase B: g = Rsym u ; x_next = Ax + Bu + w
        {
            const v2f* u2 = (const v2f*)us;
            v2f aR = v2f{0.f, 0.f}, aB = v2f{0.f, 0.f};
#pragma unroll
            for (int q = 0; q < 16; ++q) {
                v2f uq = u2[s + 4 * q];
                aR += mR[q] * uq;
                aB += mB[q] * uq;
            }
            float gv = aR.x + aR.y, bv = aB.x + aB.y;
            gv = dpp_add<0xB1>(gv); gv = dpp_add<0x4E>(gv);
            bv = dpp_add<0xB1>(bv); bv = dpp_add<0x4E>(bv);
            if (s == 0) {
                gs[r] = gv;
                float xn = axr + bv + wv;
                xnxt[r] = xn;
                ws[WSX + (t + 1) * DD + r] = xn;
            }
        }
        asm volatile("s_waitcnt lgkmcnt(0)" ::: "memory");
        __builtin_amdgcn_s_barrier();

        // ---- phase C: filter update with incremental norm tracking
        {
            const float4* g4 = (const float4*)(gs + on0);
            float4 ga = g4[0], gb = g4[1];
            float g8[8] = {ga.x, ga.y, ga.z, ga.w, gb.x, gb.y, gb.z, gb.w};
            float yg = 0.f, gp = 0.f, g2 = 0.f;
#pragma unroll
            for (int j = 0; j < 8; ++j) {
                yg += y[j] * g8[j];
                gp += p[j] * g8[j];
                g2 += g8[j] * g8[j];
            }
            yg = dpp_add<0xB1>(yg); yg = dpp_add<0x4E>(yg);
            yg = dpp_add<0x124>(yg); yg = dpp_add<0x128>(yg);
            gp = dpp_add<0xB1>(gp); gp = dpp_add<0x4E>(gp);
            gp = dpp_add<0x124>(gp); gp = dpp_add<0x128>(gp);
            g2 = dpp_add<0xB1>(g2); g2 = dpp_add<0x4E>(g2);
            g2 = dpp_add<0x124>(g2); g2 = dpp_add<0x128>(g2);
            float ny2 = ony2 - 2.f * oe * yg + oe * oe * g2;
            float yp  = oyp - oe * gp;
            float norm2 = oa * oa * om0 + 2.f * oa * yp + ofn2 * ny2;
            float nrm = sqrtf(fmaxf(norm2, 0.f));
            float sc = (nrm > BOUND_C) ? (BOUND_C / nrm) : 1.f;
            oa *= sc; ony2 = ny2 * sc * sc; oyp = yp * sc;
            float ca = os4 * oa, cy = os4 * ofn2;
#pragma unroll
            for (int j = 0; j < 8; ++j) {
                y[j] = sc * (y[j] - oe * g8[j]);
                Zl[oi * 131 + on0 + j] = ca * p[j] + cy * y[j];
            }
        }
        asm volatile("s_waitcnt lgkmcnt(0)" ::: "memory");
        __builtin_amdgcn_s_barrier();
    }
}

// Deferred, fully parallel cost: out[t] = x_t' Q x_t + u_t' R u_t
__launch_bounds__(128)
__global__ void k_cost(const float* __restrict__ Qm, const float* __restrict__ Rm,
                       const float* __restrict__ ws, float* __restrict__ out) {
    const int t = blockIdx.x, r = threadIdx.x;
    __shared__ float xv[DD], uv[DD];
    __shared__ float red[2];
    xv[r] = ws[WSX + t * DD + r];
    uv[r] = ws[WSU + t * DD + r];
    __syncthreads();
    const float4* q4 = (const float4*)(Qm + r * DD);
    const float4* r4 = (const float4*)(Rm + r * DD);
    const float4* x4 = (const float4*)xv;
    const float4* u4 = (const float4*)uv;
    float qa = 0.f, ra = 0.f;
#pragma unroll 8
    for (int j = 0; j < 32; ++j) {
        float4 qv = q4[j], xq = x4[j];
        qa += qv.x*xq.x + qv.y*xq.y + qv.z*xq.z + qv.w*xq.w;
        float4 rv = r4[j], uq = u4[j];
        ra += rv.x*uq.x + rv.y*uq.y + rv.z*uq.z + rv.w*uq.w;
    }
    float part = xv[r] * qa + uv[r] * ra;
    part = dpp_add<0xB1>(part); part = dpp_add<0x4E>(part);
    part = dpp_add<0x124>(part); part = dpp_add<0x128>(part);
    part += __shfl_xor(part, 16); part += __shfl_xor(part, 32);
    if ((r & 63) == 0) red[r >> 6] = part;
    __syncthreads();
    if (r == 0) out[t] = red[0] + red[1];
}

extern "C" void kernel_launch(void* const* d_in, const int* in_sizes, int n_in,
                              void* d_out, int out_size, void* d_ws, size_t ws_size,
                              hipStream_t stream) {
    const float* A     = (const float*)d_in[0];
    const float* B     = (const float*)d_in[1];
    const float* Q     = (const float*)d_in[2];
    const float* R     = (const float*)d_in[3];
    const float* K     = (const float*)d_in[4];
    const float* sigma = (const float*)d_in[5];
    const float* phi   = (const float*)d_in[6];
    const float* M0    = (const float*)d_in[7];
    const float* x0    = (const float*)d_in[8];
    const float* Whist = (const float*)d_in[9];
    const float* wseq  = (const float*)d_in[10];
    float* out = (float*)d_out;
    float* ws  = (float*)d_ws;

    hipLaunchKernelGGL(k_precompF, dim3(HH), dim3(DD), 0, stream, Whist, phi, sigma, ws);
    hipLaunchKernelGGL(k_precompP, dim3(HH), dim3(DD), 0, stream, M0, ws);
    hipLaunchKernelGGL(k_scan, dim3(1), dim3(512), 0, stream,
                       A, B, R, K, x0, wseq, ws);
    hipLaunchKernelGGL(k_cost, dim3(TT), dim3(DD), 0, stream, Q, R, ws, out);
}

// Round 13
// 337.780 us; speedup vs baseline: 1.2823x; 1.0941x over previous
//
#include <hip/hip_runtime.h>
#include <math.h>

#define DD 128
#define HH 32
#define MH 64
#define TT 256
#define ETA_C 1e-3f
#define BOUND_C 1.4907119849998598f   // sqrt(2/0.9)

// ws float layout:
//   F[32][128] @ 0     fn2[32] @ 8192   s4[32] @ 8224   m0n2[32] @ 8256
//   P[32][128] @ 4096
//   X store @ 8320 (257*128)   U store @ 41216 (256*128)
#define WSX 8320
#define WSU 41216

typedef float v2f __attribute__((ext_vector_type(2)));

#define KEEPV(v) asm volatile("" : "+v"(v))

__device__ __forceinline__ v2f pk_fma(v2f a, v2f b, v2f c) {
    v2f d;
    asm("v_pk_fma_f32 %0, %1, %2, %3" : "=v"(d) : "v"(a), "v"(b), "v"(c));
    return d;
}

template <int CTRL>
__device__ __forceinline__ float dpp_add(float x) {
    int y = __builtin_amdgcn_update_dpp(0, __float_as_int(x), CTRL, 0xF, 0xF, true);
    return x + __int_as_float(y);
}
// quad sum: 0xB1,0x4E.  16-lane sum: +0x124 (row_ror:4), 0x128 (row_ror:8).

__global__ void k_precompF(const float* __restrict__ W, const float* __restrict__ phi,
                           const float* __restrict__ sigma, float* __restrict__ ws) {
    int i = blockIdx.x, d = threadIdx.x;
    float acc = 0.f;
#pragma unroll
    for (int m = 0; m < MH; ++m) acc += W[d * MH + m] * phi[m * HH + i];
    ws[i * DD + d] = acc;
    __shared__ float red[DD];
    red[d] = acc * acc;
    __syncthreads();
    for (int o = 64; o > 0; o >>= 1) {
        if (d < o) red[d] += red[d + o];
        __syncthreads();
    }
    if (d == 0) {
        ws[8192 + i] = red[0];
        ws[8224 + i] = sqrtf(sqrtf(sigma[i]));
    }
}

__global__ void k_precompP(const float* __restrict__ M0, float* __restrict__ ws) {
    int i = blockIdx.x, n = threadIdx.x;
    const float* f  = ws + i * DD;
    const float* m0 = M0 + i * DD * DD + n * DD;
    float p = 0.f, sq = 0.f;
#pragma unroll 4
    for (int d = 0; d < DD; ++d) {
        float v = m0[d];
        p  += v * f[d];
        sq += v * v;
    }
    ws[4096 + i * DD + n] = p;
    __shared__ float red[DD];
    red[n] = sq;
    __syncthreads();
    for (int o = 64; o > 0; o >>= 1) {
        if (n < o) red[n] += red[n + o];
        __syncthreads();
    }
    if (n == 0) ws[8256 + i] = red[0];
}

__launch_bounds__(512)
__attribute__((amdgpu_waves_per_eu(2, 2)))
__global__ void k_scan(const float* __restrict__ Am, const float* __restrict__ Bm,
                       const float* __restrict__ Rm, const float* __restrict__ Km,
                       const float* __restrict__ x0, const float* __restrict__ wseq,
                       float* __restrict__ ws) {
    const int tid = threadIdx.x;
    const int r = tid >> 2, s = tid & 3;

    // Column-block layout: thread (r,s) owns cols {4s+16q+0..3}, q=0..7.
    // x/u broadcasts become 8 ds_read_b128 per phase (4 unique addrs/inst,
    // 16-lane broadcast each -> conflict-free).
    v2f mK[16], mA[16], mB[16], mR[16];
#pragma unroll
    for (int q = 0; q < 8; ++q) {
        const int col = 4 * s + 16 * q;
        float4 v;
        v = *(const float4*)(Km + r * DD + col);
        mK[2*q] = v2f{v.x, v.y}; mK[2*q+1] = v2f{v.z, v.w};
        v = *(const float4*)(Am + r * DD + col);
        mA[2*q] = v2f{v.x, v.y}; mA[2*q+1] = v2f{v.z, v.w};
        v = *(const float4*)(Bm + r * DD + col);
        mB[2*q] = v2f{v.x, v.y}; mB[2*q+1] = v2f{v.z, v.w};
        v = *(const float4*)(Rm + r * DD + col);
        v.x += Rm[(col + 0) * DD + r];   // Rsym = R + R^T
        v.y += Rm[(col + 1) * DD + r];
        v.z += Rm[(col + 2) * DD + r];
        v.w += Rm[(col + 3) * DD + r];
        mR[2*q] = v2f{v.x, v.y}; mR[2*q+1] = v2f{v.z, v.w};
    }
#pragma unroll
    for (int q = 0; q < 16; ++q) { KEEPV(mK[q]); KEEPV(mA[q]); KEEPV(mB[q]); KEEPV(mR[q]); }

    // Filter state: filter oi owned by 16 consecutive threads, 8 elems each.
    const int oi = tid >> 4, ol = tid & 15, on0 = ol << 3;
    float y[8], p[8];
    float oa = 1.f, ony2 = 0.f, oyp = 0.f;
    const float os4  = ws[8224 + oi];
    const float ofn2 = ws[8192 + oi];
    const float om0  = ws[8256 + oi];
    const float oe   = ETA_C * os4;

    __shared__ alignas(16) float xs[2][DD];
    __shared__ alignas(16) float us[DD], gs[DD];
    __shared__ float Zl[HH * 131];   // stride 131: z-sum reads conflict-free

#pragma unroll
    for (int j = 0; j < 8; ++j) {
        y[j] = 0.f;
        p[j] = ws[4096 + oi * DD + on0 + j];
    }
#pragma unroll
    for (int j = 0; j < 8; ++j) Zl[oi * 131 + on0 + j] = os4 * p[j];
    if (tid < DD) {
        float xv = x0[tid];
        xs[0][tid] = xv;
        ws[WSX + tid] = xv;
    }
    __syncthreads();

    float axr = 0.f;
#pragma unroll 1
    for (int t = 0; t < TT; ++t) {
        float* xcur = xs[t & 1];
        float* xnxt = xs[(t & 1) ^ 1];
        float wv = 0.f;
        if (s == 0) wv = wseq[t * DD + r];   // prefetch, consumed in phase B

        // ---- phase A: u[r] = noise[r] - (K x)[r]; (A x)[r] partial kept in reg
        {
            const float4* x4p = (const float4*)xcur;
            v2f aK = v2f{0.f, 0.f}, aA = v2f{0.f, 0.f};
#pragma unroll
            for (int q = 0; q < 8; ++q) {
                float4 xq = x4p[s + 4 * q];
                v2f lo = v2f{xq.x, xq.y}, hi = v2f{xq.z, xq.w};
                aK = pk_fma(mK[2*q],   lo, aK);
                aK = pk_fma(mK[2*q+1], hi, aK);
                aA = pk_fma(mA[2*q],   lo, aA);
                aA = pk_fma(mA[2*q+1], hi, aA);
            }
            float zp = 0.f;
#pragma unroll
            for (int j = 0; j < 8; ++j) zp += Zl[(8 * s + j) * 131 + r];
            float uval = zp - (aK.x + aK.y);
            float av = aA.x + aA.y;
            uval = dpp_add<0xB1>(uval); uval = dpp_add<0x4E>(uval);
            av   = dpp_add<0xB1>(av);   av   = dpp_add<0x4E>(av);
            if (s == 0) {
                us[r] = uval;
                ws[WSU + t * DD + r] = uval;   // for deferred cost kernel
            }
            axr = av;
        }
        asm volatile("s_waitcnt lgkmcnt(0)" ::: "memory");
        __builtin_amdgcn_s_barrier();

        // ---- phase B: g = Rsym u ; x_next = Ax + Bu + w
        {
            const float4* u4p = (const float4*)us;
            v2f aR = v2f{0.f, 0.f}, aB = v2f{0.f, 0.f};
#pragma unroll
            for (int q = 0; q < 8; ++q) {
                float4 uq = u4p[s + 4 * q];
                v2f lo = v2f{uq.x, uq.y}, hi = v2f{uq.z, uq.w};
                aR = pk_fma(mR[2*q],   lo, aR);
                aR = pk_fma(mR[2*q+1], hi, aR);
                aB = pk_fma(mB[2*q],   lo, aB);
                aB = pk_fma(mB[2*q+1], hi, aB);
            }
            float gv = aR.x + aR.y, bv = aB.x + aB.y;
            gv = dpp_add<0xB1>(gv); gv = dpp_add<0x4E>(gv);
            bv = dpp_add<0xB1>(bv); bv = dpp_add<0x4E>(bv);
            if (s == 0) {
                gs[r] = gv;
                float xn = axr + bv + wv;
                xnxt[r] = xn;
                ws[WSX + (t + 1) * DD + r] = xn;
            }
        }
        asm volatile("s_waitcnt lgkmcnt(0)" ::: "memory");
        __builtin_amdgcn_s_barrier();

        // ---- phase C: filter update with incremental norm tracking
        {
            const float4* g4 = (const float4*)(gs + on0);
            float4 ga = g4[0], gb = g4[1];
            float g8[8] = {ga.x, ga.y, ga.z, ga.w, gb.x, gb.y, gb.z, gb.w};
            float yg = 0.f, gp = 0.f, g2 = 0.f;
#pragma unroll
            for (int j = 0; j < 8; ++j) {
                yg += y[j] * g8[j];
                gp += p[j] * g8[j];
                g2 += g8[j] * g8[j];
            }
            yg = dpp_add<0xB1>(yg); yg = dpp_add<0x4E>(yg);
            yg = dpp_add<0x124>(yg); yg = dpp_add<0x128>(yg);
            gp = dpp_add<0xB1>(gp); gp = dpp_add<0x4E>(gp);
            gp = dpp_add<0x124>(gp); gp = dpp_add<0x128>(gp);
            g2 = dpp_add<0xB1>(g2); g2 = dpp_add<0x4E>(g2);
            g2 = dpp_add<0x124>(g2); g2 = dpp_add<0x128>(g2);
            float ny2 = ony2 - 2.f * oe * yg + oe * oe * g2;
            float yp  = oyp - oe * gp;
            float norm2 = oa * oa * om0 + 2.f * oa * yp + ofn2 * ny2;
            float nrm = sqrtf(fmaxf(norm2, 0.f));
            float sc = (nrm > BOUND_C) ? (BOUND_C / nrm) : 1.f;
            oa *= sc; ony2 = ny2 * sc * sc; oyp = yp * sc;
            float ca = os4 * oa, cy = os4 * ofn2;
#pragma unroll
            for (int j = 0; j < 8; ++j) {
                y[j] = sc * (y[j] - oe * g8[j]);
                Zl[oi * 131 + on0 + j] = ca * p[j] + cy * y[j];
            }
        }
        asm volatile("s_waitcnt lgkmcnt(0)" ::: "memory");
        __builtin_amdgcn_s_barrier();
    }
}

// Deferred, fully parallel cost: out[t] = x_t' Q x_t + u_t' R u_t
__launch_bounds__(128)
__global__ void k_cost(const float* __restrict__ Qm, const float* __restrict__ Rm,
                       const float* __restrict__ ws, float* __restrict__ out) {
    const int t = blockIdx.x, r = threadIdx.x;
    __shared__ alignas(16) float xv[DD], uv[DD];
    __shared__ float red[2];
    xv[r] = ws[WSX + t * DD + r];
    uv[r] = ws[WSU + t * DD + r];
    __syncthreads();
    const float4* q4 = (const float4*)(Qm + r * DD);
    const float4* r4 = (const float4*)(Rm + r * DD);
    const float4* x4 = (const float4*)xv;
    const float4* u4 = (const float4*)uv;
    float qa = 0.f, ra = 0.f;
#pragma unroll 8
    for (int j = 0; j < 32; ++j) {
        float4 qv = q4[j], xq = x4[j];
        qa += qv.x*xq.x + qv.y*xq.y + qv.z*xq.z + qv.w*xq.w;
        float4 rv = r4[j], uq = u4[j];
        ra += rv.x*uq.x + rv.y*uq.y + rv.z*uq.z + rv.w*uq.w;
    }
    float part = xv[r] * qa + uv[r] * ra;
    part = dpp_add<0xB1>(part); part = dpp_add<0x4E>(part);
    part = dpp_add<0x124>(part); part = dpp_add<0x128>(part);
    part += __shfl_xor(part, 16); part += __shfl_xor(part, 32);
    if ((r & 63) == 0) red[r >> 6] = part;
    __syncthreads();
    if (r == 0) out[t] = red[0] + red[1];
}

extern "C" void kernel_launch(void* const* d_in, const int* in_sizes, int n_in,
                              void* d_out, int out_size, void* d_ws, size_t ws_size,
                              hipStream_t stream) {
    const float* A     = (const float*)d_in[0];
    const float* B     = (const float*)d_in[1];
    const float* Q     = (const float*)d_in[2];
    const float* R     = (const float*)d_in[3];
    const float* K     = (const float*)d_in[4];
    const float* sigma = (const float*)d_in[5];
    const float* phi   = (const float*)d_in[6];
    const float* M0    = (const float*)d_in[7];
    const float* x0    = (const float*)d_in[8];
    const float* Whist = (const float*)d_in[9];
    const float* wseq  = (const float*)d_in[10];
    float* out = (float*)d_out;
    float* ws  = (float*)d_ws;

    hipLaunchKernelGGL(k_precompF, dim3(HH), dim3(DD), 0, stream, Whist, phi, sigma, ws);
    hipLaunchKernelGGL(k_precompP, dim3(HH), dim3(DD), 0, stream, M0, ws);
    hipLaunchKernelGGL(k_scan, dim3(1), dim3(512), 0, stream,
                       A, B, R, K, x0, wseq, ws);
    hipLaunchKernelGGL(k_cost, dim3(TT), dim3(DD), 0, stream, Q, R, ws, out);
}